// Round 15
// baseline (545.771 us; speedup 1.0000x reference)
//
#include <hip/hip_runtime.h>
#include <hip/hip_fp16.h>
#include <hip/hip_cooperative_groups.h>

namespace cg = cooperative_groups;

// GCN 2-layer: out = D_in^-1/2 A D_out^-1/2 (relu(D_in^-1/2 A D_out^-1/2 X W1 + b1)) W2 + b2
// Strategy: project-then-aggregate; bucket-partitioned edges, single-pass
// scatter into fixed-capacity bucket regions, per-bucket CSR finalize,
// fused aggregate+GEMM for layer 2.
// R8 354 -> R10 302 -> R12 284 -> R13 267 -> R15 249 -> R16/17 245 ->
// R19 240.6 -> R21/22 238.1 (batch-12 uint4 gathers).
// R20 REGRESSED 723us: full mega-kernel — ONE regalloc budget across
//     MFMA-heavy phases forced spills. Lesson: fuse only low-VGPR phases.
// R23: cooperative build_kernel fuses {memset, scatter, bucket_csr} (all
//     int-only, <=48 VGPR, <=6.5KB LDS) with two grid.sync()s. 6 dispatches
//     -> 4 (-2 launch gaps, -1 memset). 512 blocks (2/CU, occupancy-clamped)
//     vs old scatter's 1/CU. MFMA/gather kernels keep own register budgets.
// Aggregate floor note: each agg pass gathers 205MB cacheline-efficient at
// ~4.8 TB/s effective (L2/L3 mix) — near cache service ceiling; intra-kernel
// levers exhausted.

static inline size_t align256(size_t x) { return (x + 255) & ~(size_t)255; }

#define BKT_SHIFT 8
#define BKT_W 256              // nodes per bucket window
#define MAX_NBK 400            // LDS sizing guard (N <= 102400)
#define CAP 5120               // per-bucket region capacity (mean 4092, +16s)
#define BD_THREADS 512
#define BD_MAX_BLOCKS 512      // 2 blocks/CU target, clamped by occupancy

typedef _Float16 f16x8 __attribute__((ext_vector_type(8)));
typedef float f32x4 __attribute__((ext_vector_type(4)));

// Cooperative front-end: zero region counters -> per-block LDS hist ->
// device-atomic region reservation -> LDS-cursor scatter -> grid.sync ->
// per-bucket CSR finalize. All phases int-only (low VGPR, no spill).
__global__ __launch_bounds__(BD_THREADS)
void build_kernel(const int* __restrict__ src, const int* __restrict__ dst,
                  int* __restrict__ gcnt_d, int* __restrict__ gcnt_s,
                  int* __restrict__ ebuf, unsigned char* __restrict__ sbuf,
                  int* __restrict__ csr_src,
                  int* __restrict__ cnt_in, int* __restrict__ cnt_out,
                  int* __restrict__ row_ptr,
                  int nbk, int N, int E)
{
    cg::grid_group grid = cg::this_grid();
    const int t = threadIdx.x;
    const int b = blockIdx.x;
    const int nb = gridDim.x;

    __shared__ union {
        struct { int hd[MAX_NBK], hs[MAX_NBK], cd[MAX_NBK], cs[MAX_NBK]; } part; // 6.4KB
        struct { int cnt[BKT_W], rp[BKT_W], cur[BKT_W], cnts[BKT_W],
                 red[BD_THREADS], db; } csr;                                      // 6.2KB
    } u;

    //---- phase A: partition ----
    for (int i = b * BD_THREADS + t; i < 2 * nbk; i += nb * BD_THREADS)
        gcnt_d[i] = 0;                      // gcnt_s contiguous after gcnt_d
    for (int i = t; i < nbk; i += BD_THREADS) { u.part.hd[i] = 0; u.part.hs[i] = 0; }
    __syncthreads();
    const int slice = (E + nb - 1) / nb;
    const int beg = b * slice;
    const int iend = min(beg + slice, E);
    for (int i = beg + t; i < iend; i += BD_THREADS) {
        atomicAdd(&u.part.hd[dst[i] >> BKT_SHIFT], 1);   // LDS atomics
        atomicAdd(&u.part.hs[src[i] >> BKT_SHIFT], 1);
    }
    __syncthreads();
    __threadfence();
    grid.sync();                            // counter zeroing visible
    // reserve: ~2*nbk device atomics per block (~400K total, not per-edge)
    for (int i = t; i < nbk; i += BD_THREADS) {
        int c = u.part.hd[i];
        u.part.cd[i] = i * CAP + (c ? atomicAdd(&gcnt_d[i], c) : 0);
        c = u.part.hs[i];
        u.part.cs[i] = i * CAP + (c ? atomicAdd(&gcnt_s[i], c) : 0);
    }
    __syncthreads();
    for (int i = beg + t; i < iend; i += BD_THREADS) {   // slice L2-hot
        int d = dst[i], s = src[i];
        int pd = atomicAdd(&u.part.cd[d >> BKT_SHIFT], 1);   // LDS atomic
        ebuf[pd] = ((d & (BKT_W - 1)) << 17) | s;
        int ps = atomicAdd(&u.part.cs[s >> BKT_SHIFT], 1);   // LDS atomic
        sbuf[ps] = (unsigned char)(s & (BKT_W - 1));
    }
    __threadfence();
    grid.sync();                            // all scatter writes visible

    //---- phase B: per-bucket CSR finalize (grid-stride over buckets) ----
    for (int k = b; k < nbk; k += nb) {
        const int lo = k << BKT_SHIFT;
        const int span = min(BKT_W, N - lo);

        int s1 = 0;
        for (int i = t; i < k; i += BD_THREADS) s1 += gcnt_d[i];
        u.csr.red[t] = s1;
        __syncthreads();
        for (int off = BD_THREADS / 2; off >= 1; off >>= 1) {
            if (t < off) u.csr.red[t] += u.csr.red[t + off];
            __syncthreads();
        }
        if (t == 0) u.csr.db = u.csr.red[0];
        __syncthreads();
        const int db = u.csr.db;
        const int eb = k * CAP, ee = eb + gcnt_d[k];
        const int sb = k * CAP, se = sb + gcnt_s[k];

        if (t < BKT_W) { u.csr.cnt[t] = 0; u.csr.cnts[t] = 0; }
        __syncthreads();
        for (int i = eb + t; i < ee; i += BD_THREADS) atomicAdd(&u.csr.cnt[ebuf[i] >> 17], 1);
        for (int i = sb + t; i < se; i += BD_THREADS) atomicAdd(&u.csr.cnts[sbuf[i]], 1);
        __syncthreads();
        if (t < BKT_W) u.csr.rp[t] = u.csr.cnt[t];
        __syncthreads();
        for (int off = 1; off < BKT_W; off <<= 1) {
            int v = (t < BKT_W && t >= off) ? u.csr.rp[t - off] : 0;
            __syncthreads();
            if (t < BKT_W) u.csr.rp[t] += v;
            __syncthreads();
        }
        if (t < span) {
            row_ptr[lo + t] = db + u.csr.rp[t] - u.csr.cnt[t];
            cnt_in[lo + t]  = u.csr.cnt[t];
            cnt_out[lo + t] = u.csr.cnts[t];
        }
        __syncthreads();
        if (t < BKT_W) u.csr.cur[t] = db + u.csr.rp[t] - u.csr.cnt[t];
        __syncthreads();
        for (int i = eb + t; i < ee; i += BD_THREADS) {
            int p = ebuf[i];
            int pos = atomicAdd(&u.csr.cur[p >> 17], 1);     // LDS atomic
            csr_src[pos] = p & 0x1FFFF;
        }
        if (k == 0 && t == 0) row_ptr[N] = E;
        __syncthreads();                    // union safe for next iteration
    }
}

// MFMA GEMM: Y[n][j] = (sum_k X[n][k] * W[k][j]) * rsqrt(max(cnt_out[n],1)),
// stored fp16. hi/lo fp16 split (error ~2^-22), fp32 accumulate.
// k-contiguous b128 LDS staging = conflict-free minimum.
template <int K>
__global__ __launch_bounds__(256)
void gemm_scale_kernel(const float* __restrict__ X, const float* __restrict__ W,
                       const int* __restrict__ cnt_out,
                       __half* __restrict__ Y, int N) {
    __shared__ _Float16 Wt[2][64][K + 8];   // [hi/lo][col][k]
    const int t = threadIdx.x;
    {
        const int jj = t >> 2;             // column 0..63
        const int kb = (t & 3) * (K / 4);  // k-range base
#pragma unroll
        for (int c8 = 0; c8 < K / 4; c8 += 8) {
            float w[8];
#pragma unroll
            for (int m = 0; m < 8; ++m) w[m] = W[(kb + c8 + m) * 64 + jj];
            f16x8 hi8, lo8;
#pragma unroll
            for (int m = 0; m < 8; ++m) {
                const _Float16 h = (_Float16)w[m];
                hi8[m] = h;
                lo8[m] = (_Float16)(w[m] - (float)h);
            }
            *(f16x8*)&Wt[0][jj][kb + c8] = hi8;
            *(f16x8*)&Wt[1][jj][kb + c8] = lo8;
        }
    }
    __syncthreads();

    const int wid  = t >> 6;
    const int lane = t & 63;
    const int col  = lane & 15;
    const int kg   = (lane >> 4) * 8;

    const int rowA = blockIdx.x * 64 + wid * 16 + col;   // A-frag row
    const size_t xbase = (size_t)min(rowA, N - 1) * K;

    f32x4 acc0 = {}, acc1 = {}, acc2 = {}, acc3 = {};

#pragma unroll
    for (int ks = 0; ks < K; ks += 32) {
        float4 xa = *(const float4*)&X[xbase + ks + kg];
        float4 xb = *(const float4*)&X[xbase + ks + kg + 4];
        const float xs[8] = {xa.x, xa.y, xa.z, xa.w, xb.x, xb.y, xb.z, xb.w};
        f16x8 ahi, alo;
#pragma unroll
        for (int j = 0; j < 8; ++j) {
            const _Float16 h = (_Float16)xs[j];
            ahi[j] = h;
            alo[j] = (_Float16)(xs[j] - (float)h);
        }
#pragma unroll
        for (int tile = 0; tile < 4; ++tile) {
            const f16x8 bhi = *(const f16x8*)&Wt[0][col + 16 * tile][ks + kg];
            const f16x8 blo = *(const f16x8*)&Wt[1][col + 16 * tile][ks + kg];
            f32x4* acc = (tile == 0) ? &acc0 : (tile == 1) ? &acc1
                       : (tile == 2) ? &acc2 : &acc3;
            *acc = __builtin_amdgcn_mfma_f32_16x16x32_f16(ahi, bhi, *acc, 0, 0, 0);
            *acc = __builtin_amdgcn_mfma_f32_16x16x32_f16(alo, bhi, *acc, 0, 0, 0);
            *acc = __builtin_amdgcn_mfma_f32_16x16x32_f16(ahi, blo, *acc, 0, 0, 0);
        }
    }

    // D layout: col = lane&15, row = (lane>>4)*4 + reg   [m89-verified]
    const int rbase = blockIdx.x * 64 + wid * 16 + (lane >> 4) * 4;
#pragma unroll
    for (int r = 0; r < 4; ++r) {
        const int rr = rbase + r;
        if (rr < N) {
            const float sc = rsqrtf((float)max(cnt_out[rr], 1));
            __half* yp = &Y[(size_t)rr * 64 + col];
            yp[0]  = __float2half_rn(acc0[r] * sc);
            yp[16] = __float2half_rn(acc1[r] * sc);
            yp[32] = __float2half_rn(acc2[r] * sc);
            yp[48] = __float2half_rn(acc3[r] * sc);
        }
    }
}

// FUSED layer-1 aggregate + layer-2 GEMM. Block = 32 nodes, 256 threads.
// Phase 1 (8 lanes/node, 16B uint4 gathers, batch-12 clamped):
// h = relu(agg*rs_in+b1), hi/lo fp16 packed into LDS via f16x8 b128 stores.
// B-tile (W2) per wave in 16 VGPRs, loaded after the gather loop.
// Phase 2: wave w computes output col-tile w for both 16-node groups via
// mfma_f32_16x16x32_f16 (3-term hi/lo, fp32 acc), scaled by rs_out -> Y2.
// No early returns (clamped node ids) so barriers stay uniform.
__global__ __launch_bounds__(256)
void agg_gemm_kernel(const __half* __restrict__ Y,
                     const int* __restrict__ row_ptr,
                     const int* __restrict__ csr_src,
                     const int* __restrict__ cnt_in,
                     const int* __restrict__ cnt_out,
                     const float* __restrict__ b1,
                     const float* __restrict__ W2,
                     __half* __restrict__ Y2, int N) {
    __shared__ _Float16 Hh[32][72];
    __shared__ _Float16 Hl[32][72];
    const int t = threadIdx.x;
    const int wid  = t >> 6;
    const int lane = t & 63;
    const int col  = lane & 15;
    const int kg   = (lane >> 4) * 8;

    // ---- phase 1: aggregate, 8 lanes/node, batch-12 ----
    const int nl = t >> 3;                 // local node 0..31
    const int f8 = t & 7;                  // features 8*f8 .. 8*f8+7
    const int n  = blockIdx.x * 32 + nl;
    const int nc = min(n, N - 1);

    const int start = row_ptr[nc];
    const int end   = row_ptr[nc + 1];
    const int last  = end - 1;

    float4 acc0 = {0.f, 0.f, 0.f, 0.f}, acc1 = {0.f, 0.f, 0.f, 0.f};
    for (int e = start; e < end; e += 12) {
        int idx[12];
#pragma unroll
        for (int j = 0; j < 12; ++j) idx[j] = csr_src[min(e + j, last)];
        uint4 v[12];
#pragma unroll
        for (int j = 0; j < 12; ++j)
            v[j] = *((const uint4*)(Y + ((size_t)idx[j] << 6)) + f8);
#pragma unroll
        for (int j = 0; j < 12; ++j) {
            if (e + j < end) {
                float2 a = __half22float2(*(const __half2*)&v[j].x);
                float2 b = __half22float2(*(const __half2*)&v[j].y);
                float2 c = __half22float2(*(const __half2*)&v[j].z);
                float2 d = __half22float2(*(const __half2*)&v[j].w);
                acc0.x += a.x; acc0.y += a.y; acc0.z += b.x; acc0.w += b.y;
                acc1.x += c.x; acc1.y += c.y; acc1.z += d.x; acc1.w += d.y;
            }
        }
    }

    // issue B-tile loads now: W2[k][16*wid+col], k = kg..kg+7 and 32+kg..+7.
    // Latency hides under the H-pack VALU + barrier below.
    float wb[16];
#pragma unroll
    for (int m = 0; m < 8; ++m) {
        wb[m]     = W2[(kg + m) * 64 + 16 * wid + col];
        wb[m + 8] = W2[(32 + kg + m) * 64 + 16 * wid + col];
    }

    {
        const float sc = rsqrtf((float)max(cnt_in[nc], 1));
        const float4 bb0 = *(const float4*)&b1[8 * f8];
        const float4 bb1 = *(const float4*)&b1[8 * f8 + 4];
        float hv[8];
        hv[0] = fmaxf(acc0.x * sc + bb0.x, 0.f);
        hv[1] = fmaxf(acc0.y * sc + bb0.y, 0.f);
        hv[2] = fmaxf(acc0.z * sc + bb0.z, 0.f);
        hv[3] = fmaxf(acc0.w * sc + bb0.w, 0.f);
        hv[4] = fmaxf(acc1.x * sc + bb1.x, 0.f);
        hv[5] = fmaxf(acc1.y * sc + bb1.y, 0.f);
        hv[6] = fmaxf(acc1.z * sc + bb1.z, 0.f);
        hv[7] = fmaxf(acc1.w * sc + bb1.w, 0.f);
        f16x8 hh, hl;
#pragma unroll
        for (int q = 0; q < 8; ++q) {
            const _Float16 hi = (_Float16)hv[q];
            hh[q] = hi;
            hl[q] = (_Float16)(hv[q] - (float)hi);
        }
        *(f16x8*)&Hh[nl][8 * f8] = hh;     // b128 store, banks 8-deep
        *(f16x8*)&Hl[nl][8 * f8] = hl;
    }
    __syncthreads();

    // ---- phase 2: two 16x64 @ 64x64 MFMA groups, wave w -> col tile w ----
    f16x8 bhi0, blo0, bhi1, blo1;
#pragma unroll
    for (int m = 0; m < 8; ++m) {
        _Float16 h = (_Float16)wb[m];
        bhi0[m] = h;
        blo0[m] = (_Float16)(wb[m] - (float)h);
        h = (_Float16)wb[m + 8];
        bhi1[m] = h;
        blo1[m] = (_Float16)(wb[m + 8] - (float)h);
    }

    const int rloc = (lane >> 4) * 4;
#pragma unroll
    for (int g = 0; g < 2; ++g) {
        const f16x8 ahi0 = *(const f16x8*)&Hh[g * 16 + col][kg];
        const f16x8 alo0 = *(const f16x8*)&Hl[g * 16 + col][kg];
        const f16x8 ahi1 = *(const f16x8*)&Hh[g * 16 + col][32 + kg];
        const f16x8 alo1 = *(const f16x8*)&Hl[g * 16 + col][32 + kg];

        f32x4 acc2 = {};
        acc2 = __builtin_amdgcn_mfma_f32_16x16x32_f16(ahi0, bhi0, acc2, 0, 0, 0);
        acc2 = __builtin_amdgcn_mfma_f32_16x16x32_f16(alo0, bhi0, acc2, 0, 0, 0);
        acc2 = __builtin_amdgcn_mfma_f32_16x16x32_f16(ahi0, blo0, acc2, 0, 0, 0);
        acc2 = __builtin_amdgcn_mfma_f32_16x16x32_f16(ahi1, bhi1, acc2, 0, 0, 0);
        acc2 = __builtin_amdgcn_mfma_f32_16x16x32_f16(alo1, bhi1, acc2, 0, 0, 0);
        acc2 = __builtin_amdgcn_mfma_f32_16x16x32_f16(ahi1, blo1, acc2, 0, 0, 0);

        // D layout: col = lane&15, row = (lane>>4)*4 + reg
#pragma unroll
        for (int r = 0; r < 4; ++r) {
            const int rr = blockIdx.x * 32 + g * 16 + rloc + r;
            if (rr < N) {
                const float s2 = rsqrtf((float)max(cnt_out[rr], 1));
                Y2[(size_t)rr * 64 + 16 * wid + col] = __float2half_rn(acc2[r] * s2);
            }
        }
    }
}

// out[n][f] = (sum_{in-edges} Y[src][f]) * rsqrt(max(cnt_in[n],1)) + bias[f]
// 8 lanes per node (8 nodes/wave); lane = 8 features (16B uint4 gather).
// Clamped batch-12: EVERY row runs with 12x16B gathers in flight.
template <bool RELU>
__global__ __launch_bounds__(256)
void aggregate_kernel(const __half* __restrict__ Y,
                      const int* __restrict__ row_ptr,
                      const int* __restrict__ csr_src,
                      const int* __restrict__ cnt_in,
                      const float* __restrict__ bias,
                      float* __restrict__ out, int N) {
    const int n = blockIdx.x * 32 + (threadIdx.x >> 3);
    if (n >= N) return;
    const int f8 = threadIdx.x & 7;           // features 8*f8 .. 8*f8+7

    const int start = row_ptr[n];
    const int end   = row_ptr[n + 1];
    const int last  = end - 1;

    float4 acc0 = {0.f, 0.f, 0.f, 0.f}, acc1 = {0.f, 0.f, 0.f, 0.f};
    for (int e = start; e < end; e += 12) {
        int idx[12];
#pragma unroll
        for (int j = 0; j < 12; ++j) idx[j] = csr_src[min(e + j, last)];
        uint4 v[12];
#pragma unroll
        for (int j = 0; j < 12; ++j)
            v[j] = *((const uint4*)(Y + ((size_t)idx[j] << 6)) + f8);
#pragma unroll
        for (int j = 0; j < 12; ++j) {
            if (e + j < end) {
                float2 a = __half22float2(*(const __half2*)&v[j].x);
                float2 b = __half22float2(*(const __half2*)&v[j].y);
                float2 c = __half22float2(*(const __half2*)&v[j].z);
                float2 d = __half22float2(*(const __half2*)&v[j].w);
                acc0.x += a.x; acc0.y += a.y; acc0.z += b.x; acc0.w += b.y;
                acc1.x += c.x; acc1.y += c.y; acc1.z += d.x; acc1.w += d.y;
            }
        }
    }

    const float sc = rsqrtf((float)max(cnt_in[n], 1));
    const float4 bb0 = *(const float4*)&bias[8 * f8];
    const float4 bb1 = *(const float4*)&bias[8 * f8 + 4];
    float4 o0, o1;
    o0.x = acc0.x * sc + bb0.x;
    o0.y = acc0.y * sc + bb0.y;
    o0.z = acc0.z * sc + bb0.z;
    o0.w = acc0.w * sc + bb0.w;
    o1.x = acc1.x * sc + bb1.x;
    o1.y = acc1.y * sc + bb1.y;
    o1.z = acc1.z * sc + bb1.z;
    o1.w = acc1.w * sc + bb1.w;
    if (RELU) {
        o0.x = fmaxf(o0.x, 0.f); o0.y = fmaxf(o0.y, 0.f);
        o0.z = fmaxf(o0.z, 0.f); o0.w = fmaxf(o0.w, 0.f);
        o1.x = fmaxf(o1.x, 0.f); o1.y = fmaxf(o1.y, 0.f);
        o1.z = fmaxf(o1.z, 0.f); o1.w = fmaxf(o1.w, 0.f);
    }
    float4* op = (float4*)&out[((size_t)n << 6) + 8 * f8];
    op[0] = o0;
    op[1] = o1;
}

extern "C" void kernel_launch(void* const* d_in, const int* in_sizes, int n_in,
                              void* d_out, int out_size, void* d_ws, size_t ws_size,
                              hipStream_t stream) {
    const int*   src = (const int*)d_in[1];
    const int*   dst = (const int*)d_in[2];
    const float* x   = (const float*)d_in[0];
    const float* W1  = (const float*)d_in[3];
    const float* b1  = (const float*)d_in[4];
    const float* W2  = (const float*)d_in[5];
    const float* b2  = (const float*)d_in[6];
    float* out = (float*)d_out;

    int N = in_sizes[0] / 128;   // 100000
    int E = in_sizes[1];         // 1600000
    int nbk = (N + BKT_W - 1) >> BKT_SHIFT;                // 391 buckets

    // Workspace (~45 MB of ~268 MB). d_out written only by the final agg.
    char* ws = (char*)d_ws;
    size_t off = 0;
    __half* Y       = (__half*)(ws + off); off = align256(off + (size_t)N * 64 * sizeof(__half));
    __half* Y2      = (__half*)(ws + off); off = align256(off + (size_t)N * 64 * sizeof(__half));
    int* csr_src    = (int*)(ws + off);    off = align256(off + (size_t)E * sizeof(int));
    int* ebuf       = (int*)(ws + off);    off = align256(off + (size_t)nbk * CAP * sizeof(int));
    unsigned char* sbuf = (unsigned char*)(ws + off); off = align256(off + (size_t)nbk * CAP);
    int* gcnt       = (int*)(ws + off);    off = align256(off + (size_t)2 * nbk * sizeof(int));
    int* gcnt_d     = gcnt;                // gcnt_s contiguous after gcnt_d
    int* gcnt_s     = gcnt + nbk;          // (build_kernel zeroes both)
    int* cnt_out    = (int*)(ws + off);    off = align256(off + (size_t)N * sizeof(int));
    int* cnt_in     = (int*)(ws + off);    off = align256(off + (size_t)N * sizeof(int));
    int* row_ptr    = (int*)(ws + off);    off = align256(off + (size_t)(N + 1) * sizeof(int));

    // Co-residency-safe grid size (cached): grid.sync must not deadlock.
    static int s_blocks = -1;
    if (s_blocks < 0) {
        hipDeviceProp_t prop;
        hipGetDeviceProperties(&prop, 0);
        int nb = 0;
        hipOccupancyMaxActiveBlocksPerMultiprocessor(&nb, build_kernel, BD_THREADS, 0);
        if (nb < 1) nb = 1;
        long cap = (long)nb * prop.multiProcessorCount;
        s_blocks = (int)((cap < BD_MAX_BLOCKS) ? cap : BD_MAX_BLOCKS);
    }

    // Front-end: partition + CSR build in ONE cooperative dispatch.
    void* args[] = {&src, &dst, &gcnt_d, &gcnt_s, &ebuf, &sbuf,
                    &csr_src, &cnt_in, &cnt_out, &row_ptr, &nbk, &N, &E};
    hipLaunchCooperativeKernel((const void*)build_kernel, dim3(s_blocks),
                               dim3(BD_THREADS), args, 0, stream);

    const int gemm_blocks = (N + 63) / 64;
    const int agg_blocks  = (N + 31) / 32;

    // Layer 1 GEMM: Y = fp16[(X @ W1) * rs_out]
    gemm_scale_kernel<128><<<gemm_blocks, 256, 0, stream>>>(x, W1, cnt_out, Y, N);
    // Fused: agg1 (+b1, relu) -> hidden in LDS -> @W2 * rs_out -> Y2 fp16
    agg_gemm_kernel<<<agg_blocks, 256, 0, stream>>>(Y, row_ptr, csr_src,
                                                    cnt_in, cnt_out, b1, W2, Y2, N);
    // Layer 2 aggregate: out = agg(Y2) * rs_in + b2
    aggregate_kernel<false><<<agg_blocks, 256, 0, stream>>>(Y2, row_ptr, csr_src,
                                                            cnt_in, b2, out, N);
}

// Round 16
// 236.096 us; speedup vs baseline: 2.3117x; 2.3117x over previous
//
#include <hip/hip_runtime.h>
#include <hip/hip_fp16.h>

// GCN 2-layer: out = D_in^-1/2 A D_out^-1/2 (relu(D_in^-1/2 A D_out^-1/2 X W1 + b1)) W2 + b2
// Strategy: project-then-aggregate; bucket-partitioned edges, single-pass
// scatter into fixed-capacity bucket regions, per-bucket CSR finalize,
// fused aggregate+GEMM for layer 2.
// R8 354 -> R10 302 -> R12 284 -> R13 267 -> R15 249 -> R16/17 245 ->
// R19 240.6 -> R21/22 238.1 (batch-12 uint4 gathers) = CHAMPION.
// R20 REGRESSED 723us: full mega-kernel — ONE regalloc budget across
//     MFMA-heavy phases forced spills (FETCH/WRITE +100MB scratch).
// R23 REGRESSED 545us: cooperative front-end fusion. build_kernel 350us at
//     VALUBusy 0.7% with only ~100MB traffic -> grid.sync costs ~150-175us
//     PER SYNC on MI355X (s_sleep spin; waves deschedule, show idle).
//     Both fusion mechanisms measured dead: mega-kernel = regalloc poison,
//     coop sync = barrier latency. Serial 6-dispatch chain is the floor.
// R24: pure revert to the R21/R22 champion.
// Floor analysis: own kernels ~135us (2 gather passes ~43+36us each: 205MB
// cacheline-efficient random gathers at ~4.8TB/s L3/L2-mix service ceiling,
// working set 12.8MB > 4MB XCD L2; CSR build ~40us LDS-atomic-bound; GEMM
// ~14us near HBM floor) + ~100us serial-dispatch structure. Next levers
// would need fp8 hidden state (accuracy risk) or a cheap grid barrier.

static inline size_t align256(size_t x) { return (x + 255) & ~(size_t)255; }

#define BKT_SHIFT 8
#define BKT_W 256              // nodes per bucket window
#define MAX_NBK 400            // LDS sizing guard (N <= 102400)
#define CAP 5120               // per-bucket region capacity (mean 4092, +16s)
#define SC_BLOCKS 256          // scatter blocks (1 per CU)
#define SC_THREADS 512

typedef _Float16 f16x8 __attribute__((ext_vector_type(8)));
typedef float f32x4 __attribute__((ext_vector_type(4)));

// A: single-pass partition. Per block: LDS hist of slice -> device-atomic
// region reservation (one per touched bucket) -> LDS-cursor scatter.
__global__ __launch_bounds__(SC_THREADS)
void scatter_atomic_kernel(const int* __restrict__ src, const int* __restrict__ dst,
                           int* __restrict__ gcnt_d, int* __restrict__ gcnt_s,
                           int* __restrict__ ebuf, unsigned char* __restrict__ sbuf,
                           int nbk, int E, int slice_len) {
    __shared__ int hd[MAX_NBK];
    __shared__ int hs[MAX_NBK];
    __shared__ int cur_d[MAX_NBK];
    __shared__ int cur_s[MAX_NBK];
    const int b = blockIdx.x;
    const int t = threadIdx.x;
    for (int i = t; i < nbk; i += SC_THREADS) { hd[i] = 0; hs[i] = 0; }
    __syncthreads();
    const int beg = b * slice_len;
    const int end = min(beg + slice_len, E);
    for (int i = beg + t; i < end; i += SC_THREADS) {
        atomicAdd(&hd[dst[i] >> BKT_SHIFT], 1);   // LDS atomic (int: native)
        atomicAdd(&hs[src[i] >> BKT_SHIFT], 1);
    }
    __syncthreads();
    // reserve: ~2*nbk device atomics per block (~200K total, not per-edge)
    for (int i = t; i < nbk; i += SC_THREADS) {
        int c = hd[i];
        cur_d[i] = i * CAP + (c ? atomicAdd(&gcnt_d[i], c) : 0);
        c = hs[i];
        cur_s[i] = i * CAP + (c ? atomicAdd(&gcnt_s[i], c) : 0);
    }
    __syncthreads();
    for (int i = beg + t; i < end; i += SC_THREADS) {  // slice is L2-hot now
        int d = dst[i], s = src[i];
        int pd = atomicAdd(&cur_d[d >> BKT_SHIFT], 1);   // LDS atomic
        ebuf[pd] = ((d & (BKT_W - 1)) << 17) | s;
        int ps = atomicAdd(&cur_s[s >> BKT_SHIFT], 1);   // LDS atomic
        sbuf[ps] = (unsigned char)(s & (BKT_W - 1));
    }
}

// B: per-bucket finalize (512 threads). db = prefix over gcnt_d; emits
// cnt_in, cnt_out, row_ptr, csr_src (contiguous CSR, bucket-local writes).
__global__ __launch_bounds__(512)
void bucket_csr_kernel(const int* __restrict__ ebuf,
                       const unsigned char* __restrict__ sbuf,
                       const int* __restrict__ gcnt_d, const int* __restrict__ gcnt_s,
                       int* __restrict__ csr_src,
                       int* __restrict__ cnt_in, int* __restrict__ cnt_out,
                       int* __restrict__ row_ptr,
                       int nbk, int N, int E) {
    __shared__ int cnt[BKT_W];
    __shared__ int rp[BKT_W];
    __shared__ int cur[BKT_W];
    __shared__ int cnts[BKT_W];
    __shared__ int red[512];
    __shared__ int sh_db;
    const int k = blockIdx.x;
    const int lo = k << BKT_SHIFT;
    const int span = min(BKT_W, N - lo);
    const int t = threadIdx.x;

    // db = sum gcnt_d[0..k)
    int s1 = 0;
    for (int i = t; i < k; i += 512) s1 += gcnt_d[i];
    red[t] = s1;
    __syncthreads();
    for (int off = 256; off >= 1; off >>= 1) {
        if (t < off) red[t] += red[t + off];
        __syncthreads();
    }
    if (t == 0) sh_db = red[0];
    __syncthreads();
    const int db = sh_db;
    const int eb = k * CAP, ee = eb + gcnt_d[k];
    const int sb = k * CAP, se = sb + gcnt_s[k];

    if (t < BKT_W) { cnt[t] = 0; cnts[t] = 0; }
    __syncthreads();
    for (int i = eb + t; i < ee; i += 512) atomicAdd(&cnt[ebuf[i] >> 17], 1);
    for (int i = sb + t; i < se; i += 512) atomicAdd(&cnts[sbuf[i]], 1);
    __syncthreads();
    if (t < BKT_W) rp[t] = cnt[t];
    __syncthreads();
    for (int off = 1; off < BKT_W; off <<= 1) {
        int v = (t < BKT_W && t >= off) ? rp[t - off] : 0;
        __syncthreads();
        if (t < BKT_W) rp[t] += v;
        __syncthreads();
    }
    if (t < span) {
        row_ptr[lo + t] = db + rp[t] - cnt[t];
        cnt_in[lo + t]  = cnt[t];
        cnt_out[lo + t] = cnts[t];
    }
    __syncthreads();
    if (t < BKT_W) cur[t] = db + rp[t] - cnt[t];
    __syncthreads();
    for (int i = eb + t; i < ee; i += 512) {
        int p = ebuf[i];
        int pos = atomicAdd(&cur[p >> 17], 1);           // LDS atomic
        csr_src[pos] = p & 0x1FFFF;
    }
    if (k == 0 && t == 0) row_ptr[N] = E;
}

// MFMA GEMM: Y[n][j] = (sum_k X[n][k] * W[k][j]) * rsqrt(max(cnt_out[n],1)),
// stored fp16. hi/lo fp16 split (error ~2^-22), fp32 accumulate.
// k-contiguous b128 LDS staging = conflict-free minimum.
template <int K>
__global__ __launch_bounds__(256)
void gemm_scale_kernel(const float* __restrict__ X, const float* __restrict__ W,
                       const int* __restrict__ cnt_out,
                       __half* __restrict__ Y, int N) {
    __shared__ _Float16 Wt[2][64][K + 8];   // [hi/lo][col][k]
    const int t = threadIdx.x;
    {
        const int jj = t >> 2;             // column 0..63
        const int kb = (t & 3) * (K / 4);  // k-range base
#pragma unroll
        for (int c8 = 0; c8 < K / 4; c8 += 8) {
            float w[8];
#pragma unroll
            for (int m = 0; m < 8; ++m) w[m] = W[(kb + c8 + m) * 64 + jj];
            f16x8 hi8, lo8;
#pragma unroll
            for (int m = 0; m < 8; ++m) {
                const _Float16 h = (_Float16)w[m];
                hi8[m] = h;
                lo8[m] = (_Float16)(w[m] - (float)h);
            }
            *(f16x8*)&Wt[0][jj][kb + c8] = hi8;
            *(f16x8*)&Wt[1][jj][kb + c8] = lo8;
        }
    }
    __syncthreads();

    const int wid  = t >> 6;
    const int lane = t & 63;
    const int col  = lane & 15;
    const int kg   = (lane >> 4) * 8;

    const int rowA = blockIdx.x * 64 + wid * 16 + col;   // A-frag row
    const size_t xbase = (size_t)min(rowA, N - 1) * K;

    f32x4 acc0 = {}, acc1 = {}, acc2 = {}, acc3 = {};

#pragma unroll
    for (int ks = 0; ks < K; ks += 32) {
        float4 xa = *(const float4*)&X[xbase + ks + kg];
        float4 xb = *(const float4*)&X[xbase + ks + kg + 4];
        const float xs[8] = {xa.x, xa.y, xa.z, xa.w, xb.x, xb.y, xb.z, xb.w};
        f16x8 ahi, alo;
#pragma unroll
        for (int j = 0; j < 8; ++j) {
            const _Float16 h = (_Float16)xs[j];
            ahi[j] = h;
            alo[j] = (_Float16)(xs[j] - (float)h);
        }
#pragma unroll
        for (int tile = 0; tile < 4; ++tile) {
            const f16x8 bhi = *(const f16x8*)&Wt[0][col + 16 * tile][ks + kg];
            const f16x8 blo = *(const f16x8*)&Wt[1][col + 16 * tile][ks + kg];
            f32x4* acc = (tile == 0) ? &acc0 : (tile == 1) ? &acc1
                       : (tile == 2) ? &acc2 : &acc3;
            *acc = __builtin_amdgcn_mfma_f32_16x16x32_f16(ahi, bhi, *acc, 0, 0, 0);
            *acc = __builtin_amdgcn_mfma_f32_16x16x32_f16(alo, bhi, *acc, 0, 0, 0);
            *acc = __builtin_amdgcn_mfma_f32_16x16x32_f16(ahi, blo, *acc, 0, 0, 0);
        }
    }

    // D layout: col = lane&15, row = (lane>>4)*4 + reg   [m89-verified]
    const int rbase = blockIdx.x * 64 + wid * 16 + (lane >> 4) * 4;
#pragma unroll
    for (int r = 0; r < 4; ++r) {
        const int rr = rbase + r;
        if (rr < N) {
            const float sc = rsqrtf((float)max(cnt_out[rr], 1));
            __half* yp = &Y[(size_t)rr * 64 + col];
            yp[0]  = __float2half_rn(acc0[r] * sc);
            yp[16] = __float2half_rn(acc1[r] * sc);
            yp[32] = __float2half_rn(acc2[r] * sc);
            yp[48] = __float2half_rn(acc3[r] * sc);
        }
    }
}

// FUSED layer-1 aggregate + layer-2 GEMM. Block = 32 nodes, 256 threads.
// Phase 1 (8 lanes/node, 16B uint4 gathers, batch-12 clamped):
// h = relu(agg*rs_in+b1), hi/lo fp16 packed into LDS via f16x8 b128 stores.
// B-tile (W2) per wave in 16 VGPRs, loaded after the gather loop.
// Phase 2: wave w computes output col-tile w for both 16-node groups via
// mfma_f32_16x16x32_f16 (3-term hi/lo, fp32 acc), scaled by rs_out -> Y2.
// No early returns (clamped node ids) so barriers stay uniform.
__global__ __launch_bounds__(256)
void agg_gemm_kernel(const __half* __restrict__ Y,
                     const int* __restrict__ row_ptr,
                     const int* __restrict__ csr_src,
                     const int* __restrict__ cnt_in,
                     const int* __restrict__ cnt_out,
                     const float* __restrict__ b1,
                     const float* __restrict__ W2,
                     __half* __restrict__ Y2, int N) {
    __shared__ _Float16 Hh[32][72];
    __shared__ _Float16 Hl[32][72];
    const int t = threadIdx.x;
    const int wid  = t >> 6;
    const int lane = t & 63;
    const int col  = lane & 15;
    const int kg   = (lane >> 4) * 8;

    // ---- phase 1: aggregate, 8 lanes/node, batch-12 ----
    const int nl = t >> 3;                 // local node 0..31
    const int f8 = t & 7;                  // features 8*f8 .. 8*f8+7
    const int n  = blockIdx.x * 32 + nl;
    const int nc = min(n, N - 1);

    const int start = row_ptr[nc];
    const int end   = row_ptr[nc + 1];
    const int last  = end - 1;

    float4 acc0 = {0.f, 0.f, 0.f, 0.f}, acc1 = {0.f, 0.f, 0.f, 0.f};
    for (int e = start; e < end; e += 12) {
        int idx[12];
#pragma unroll
        for (int j = 0; j < 12; ++j) idx[j] = csr_src[min(e + j, last)];
        uint4 v[12];
#pragma unroll
        for (int j = 0; j < 12; ++j)
            v[j] = *((const uint4*)(Y + ((size_t)idx[j] << 6)) + f8);
#pragma unroll
        for (int j = 0; j < 12; ++j) {
            if (e + j < end) {
                float2 a = __half22float2(*(const __half2*)&v[j].x);
                float2 b = __half22float2(*(const __half2*)&v[j].y);
                float2 c = __half22float2(*(const __half2*)&v[j].z);
                float2 d = __half22float2(*(const __half2*)&v[j].w);
                acc0.x += a.x; acc0.y += a.y; acc0.z += b.x; acc0.w += b.y;
                acc1.x += c.x; acc1.y += c.y; acc1.z += d.x; acc1.w += d.y;
            }
        }
    }

    // issue B-tile loads now: W2[k][16*wid+col], k = kg..kg+7 and 32+kg..+7.
    // Latency hides under the H-pack VALU + barrier below.
    float wb[16];
#pragma unroll
    for (int m = 0; m < 8; ++m) {
        wb[m]     = W2[(kg + m) * 64 + 16 * wid + col];
        wb[m + 8] = W2[(32 + kg + m) * 64 + 16 * wid + col];
    }

    {
        const float sc = rsqrtf((float)max(cnt_in[nc], 1));
        const float4 bb0 = *(const float4*)&b1[8 * f8];
        const float4 bb1 = *(const float4*)&b1[8 * f8 + 4];
        float hv[8];
        hv[0] = fmaxf(acc0.x * sc + bb0.x, 0.f);
        hv[1] = fmaxf(acc0.y * sc + bb0.y, 0.f);
        hv[2] = fmaxf(acc0.z * sc + bb0.z, 0.f);
        hv[3] = fmaxf(acc0.w * sc + bb0.w, 0.f);
        hv[4] = fmaxf(acc1.x * sc + bb1.x, 0.f);
        hv[5] = fmaxf(acc1.y * sc + bb1.y, 0.f);
        hv[6] = fmaxf(acc1.z * sc + bb1.z, 0.f);
        hv[7] = fmaxf(acc1.w * sc + bb1.w, 0.f);
        f16x8 hh, hl;
#pragma unroll
        for (int q = 0; q < 8; ++q) {
            const _Float16 hi = (_Float16)hv[q];
            hh[q] = hi;
            hl[q] = (_Float16)(hv[q] - (float)hi);
        }
        *(f16x8*)&Hh[nl][8 * f8] = hh;     // b128 store, banks 8-deep
        *(f16x8*)&Hl[nl][8 * f8] = hl;
    }
    __syncthreads();

    // ---- phase 2: two 16x64 @ 64x64 MFMA groups, wave w -> col tile w ----
    f16x8 bhi0, blo0, bhi1, blo1;
#pragma unroll
    for (int m = 0; m < 8; ++m) {
        _Float16 h = (_Float16)wb[m];
        bhi0[m] = h;
        blo0[m] = (_Float16)(wb[m] - (float)h);
        h = (_Float16)wb[m + 8];
        bhi1[m] = h;
        blo1[m] = (_Float16)(wb[m + 8] - (float)h);
    }

    const int rloc = (lane >> 4) * 4;
#pragma unroll
    for (int g = 0; g < 2; ++g) {
        const f16x8 ahi0 = *(const f16x8*)&Hh[g * 16 + col][kg];
        const f16x8 alo0 = *(const f16x8*)&Hl[g * 16 + col][kg];
        const f16x8 ahi1 = *(const f16x8*)&Hh[g * 16 + col][32 + kg];
        const f16x8 alo1 = *(const f16x8*)&Hl[g * 16 + col][32 + kg];

        f32x4 acc2 = {};
        acc2 = __builtin_amdgcn_mfma_f32_16x16x32_f16(ahi0, bhi0, acc2, 0, 0, 0);
        acc2 = __builtin_amdgcn_mfma_f32_16x16x32_f16(alo0, bhi0, acc2, 0, 0, 0);
        acc2 = __builtin_amdgcn_mfma_f32_16x16x32_f16(ahi0, blo0, acc2, 0, 0, 0);
        acc2 = __builtin_amdgcn_mfma_f32_16x16x32_f16(ahi1, bhi1, acc2, 0, 0, 0);
        acc2 = __builtin_amdgcn_mfma_f32_16x16x32_f16(alo1, bhi1, acc2, 0, 0, 0);
        acc2 = __builtin_amdgcn_mfma_f32_16x16x32_f16(ahi1, blo1, acc2, 0, 0, 0);

        // D layout: col = lane&15, row = (lane>>4)*4 + reg
#pragma unroll
        for (int r = 0; r < 4; ++r) {
            const int rr = blockIdx.x * 32 + g * 16 + rloc + r;
            if (rr < N) {
                const float s2 = rsqrtf((float)max(cnt_out[rr], 1));
                Y2[(size_t)rr * 64 + 16 * wid + col] = __float2half_rn(acc2[r] * s2);
            }
        }
    }
}

// out[n][f] = (sum_{in-edges} Y[src][f]) * rsqrt(max(cnt_in[n],1)) + bias[f]
// 8 lanes per node (8 nodes/wave); lane = 8 features (16B uint4 gather).
// Clamped batch-12: EVERY row runs with 12x16B gathers in flight.
template <bool RELU>
__global__ __launch_bounds__(256)
void aggregate_kernel(const __half* __restrict__ Y,
                      const int* __restrict__ row_ptr,
                      const int* __restrict__ csr_src,
                      const int* __restrict__ cnt_in,
                      const float* __restrict__ bias,
                      float* __restrict__ out, int N) {
    const int n = blockIdx.x * 32 + (threadIdx.x >> 3);
    if (n >= N) return;
    const int f8 = threadIdx.x & 7;           // features 8*f8 .. 8*f8+7

    const int start = row_ptr[n];
    const int end   = row_ptr[n + 1];
    const int last  = end - 1;

    float4 acc0 = {0.f, 0.f, 0.f, 0.f}, acc1 = {0.f, 0.f, 0.f, 0.f};
    for (int e = start; e < end; e += 12) {
        int idx[12];
#pragma unroll
        for (int j = 0; j < 12; ++j) idx[j] = csr_src[min(e + j, last)];
        uint4 v[12];
#pragma unroll
        for (int j = 0; j < 12; ++j)
            v[j] = *((const uint4*)(Y + ((size_t)idx[j] << 6)) + f8);
#pragma unroll
        for (int j = 0; j < 12; ++j) {
            if (e + j < end) {
                float2 a = __half22float2(*(const __half2*)&v[j].x);
                float2 b = __half22float2(*(const __half2*)&v[j].y);
                float2 c = __half22float2(*(const __half2*)&v[j].z);
                float2 d = __half22float2(*(const __half2*)&v[j].w);
                acc0.x += a.x; acc0.y += a.y; acc0.z += b.x; acc0.w += b.y;
                acc1.x += c.x; acc1.y += c.y; acc1.z += d.x; acc1.w += d.y;
            }
        }
    }

    const float sc = rsqrtf((float)max(cnt_in[n], 1));
    const float4 bb0 = *(const float4*)&bias[8 * f8];
    const float4 bb1 = *(const float4*)&bias[8 * f8 + 4];
    float4 o0, o1;
    o0.x = acc0.x * sc + bb0.x;
    o0.y = acc0.y * sc + bb0.y;
    o0.z = acc0.z * sc + bb0.z;
    o0.w = acc0.w * sc + bb0.w;
    o1.x = acc1.x * sc + bb1.x;
    o1.y = acc1.y * sc + bb1.y;
    o1.z = acc1.z * sc + bb1.z;
    o1.w = acc1.w * sc + bb1.w;
    if (RELU) {
        o0.x = fmaxf(o0.x, 0.f); o0.y = fmaxf(o0.y, 0.f);
        o0.z = fmaxf(o0.z, 0.f); o0.w = fmaxf(o0.w, 0.f);
        o1.x = fmaxf(o1.x, 0.f); o1.y = fmaxf(o1.y, 0.f);
        o1.z = fmaxf(o1.z, 0.f); o1.w = fmaxf(o1.w, 0.f);
    }
    float4* op = (float4*)&out[((size_t)n << 6) + 8 * f8];
    op[0] = o0;
    op[1] = o1;
}

extern "C" void kernel_launch(void* const* d_in, const int* in_sizes, int n_in,
                              void* d_out, int out_size, void* d_ws, size_t ws_size,
                              hipStream_t stream) {
    const float* x   = (const float*)d_in[0];
    const int*   src = (const int*)d_in[1];
    const int*   dst = (const int*)d_in[2];
    const float* W1  = (const float*)d_in[3];
    const float* b1  = (const float*)d_in[4];
    const float* W2  = (const float*)d_in[5];
    const float* b2  = (const float*)d_in[6];
    float* out = (float*)d_out;

    const int N = in_sizes[0] / 128;   // 100000
    const int E = in_sizes[1];         // 1600000

    const int nbk = (N + BKT_W - 1) >> BKT_SHIFT;          // 391 buckets

    // Workspace (~45 MB of ~268 MB). d_out written only by the final agg.
    char* ws = (char*)d_ws;
    size_t off = 0;
    __half* Y       = (__half*)(ws + off); off = align256(off + (size_t)N * 64 * sizeof(__half));
    __half* Y2      = (__half*)(ws + off); off = align256(off + (size_t)N * 64 * sizeof(__half));
    int* csr_src    = (int*)(ws + off);    off = align256(off + (size_t)E * sizeof(int));
    int* ebuf       = (int*)(ws + off);    off = align256(off + (size_t)nbk * CAP * sizeof(int));
    unsigned char* sbuf = (unsigned char*)(ws + off); off = align256(off + (size_t)nbk * CAP);
    int* gcnt       = (int*)(ws + off);    off = align256(off + (size_t)2 * nbk * sizeof(int));
    int* gcnt_d     = gcnt;
    int* gcnt_s     = gcnt + nbk;
    int* cnt_out    = (int*)(ws + off);    off = align256(off + (size_t)N * sizeof(int));
    int* cnt_in     = (int*)(ws + off);    off = align256(off + (size_t)N * sizeof(int));
    int* row_ptr    = (int*)(ws + off);    off = align256(off + (size_t)(N + 1) * sizeof(int));

    const int pslice = (E + SC_BLOCKS - 1) / SC_BLOCKS;

    // Single-pass bucket partition (region counters zeroed first, one fill)
    hipMemsetAsync(gcnt, 0, (size_t)2 * nbk * sizeof(int), stream);
    scatter_atomic_kernel<<<SC_BLOCKS, SC_THREADS, 0, stream>>>(
        src, dst, gcnt_d, gcnt_s, ebuf, sbuf, nbk, E, pslice);
    bucket_csr_kernel<<<nbk, 512, 0, stream>>>(ebuf, sbuf, gcnt_d, gcnt_s, csr_src,
                                               cnt_in, cnt_out, row_ptr, nbk, N, E);

    const int gemm_blocks = (N + 63) / 64;
    const int agg_blocks  = (N + 31) / 32;

    // Layer 1 GEMM: Y = fp16[(X @ W1) * rs_out]
    gemm_scale_kernel<128><<<gemm_blocks, 256, 0, stream>>>(x, W1, cnt_out, Y, N);
    // Fused: agg1 (+b1, relu) -> hidden in LDS -> @W2 * rs_out -> Y2 fp16
    agg_gemm_kernel<<<agg_blocks, 256, 0, stream>>>(Y, row_ptr, csr_src,
                                                    cnt_in, cnt_out, b1, W2, Y2, N);
    // Layer 2 aggregate: out = agg(Y2) * rs_in + b2
    aggregate_kernel<false><<<agg_blocks, 256, 0, stream>>>(Y2, row_ptr, csr_src,
                                                            cnt_in, b2, out, N);
}